// Round 1
// baseline (44.074 us; speedup 1.0000x reference)
//
#include <hip/hip_runtime.h>
#include <math.h>

#define EPS 1e-8f

constexpr int B = 32, N = 1024, M = 128, H = 2;

constexpr int ROWS_A   = 32;            // rows of L per block in kernel A
constexpr int CHUNKS_A = N / ROWS_A;    // 32 blocks per batch
constexpr int ROWS_C2   = 64;           // rows of memory per block in kernel C2
constexpr int CHUNKS_C2 = N / ROWS_C2;  // 16

// -------- Kernel A: one pass over L computes f = L w  and partials of b = L^T w --------
__global__ __launch_bounds__(256) void kA(const float* __restrict__ L,
                                          const float* __restrict__ Wold,
                                          float* __restrict__ f,
                                          float* __restrict__ bpart) {
    int bid   = blockIdx.x;
    int b     = bid / CHUNKS_A;
    int chunk = bid % CHUNKS_A;
    int t     = threadIdx.x;
    int lane  = t & 63, wave = t >> 6;

    __shared__ float sw[N];          // W_old[b]
    __shared__ float lds_b[4][N];    // per-wave column partials

    reinterpret_cast<float4*>(sw)[t] =
        reinterpret_cast<const float4*>(Wold + (size_t)b * N)[t];
    __syncthreads();

    // each lane owns columns (lane + 64*s)*4 .. +3, s = 0..3  (covers all 1024 cols per wave)
    float4 wreg[4];
    float4 bacc[4];
#pragma unroll
    for (int s = 0; s < 4; ++s) {
        wreg[s] = reinterpret_cast<float4*>(sw)[lane + 64 * s];
        bacc[s] = make_float4(0.f, 0.f, 0.f, 0.f);
    }

    const float* Lb = L + (size_t)b * N * N;
    int r0 = chunk * ROWS_A;
    for (int r = wave; r < ROWS_A; r += 4) {          // wave handles every 4th row
        int i = r0 + r;
        const float4* row = reinterpret_cast<const float4*>(Lb + (size_t)i * N);
        float wi = sw[i];
        float p  = 0.f;
#pragma unroll
        for (int s = 0; s < 4; ++s) {
            float4 v = row[lane + 64 * s];
            p += v.x * wreg[s].x + v.y * wreg[s].y + v.z * wreg[s].z + v.w * wreg[s].w;
            bacc[s].x += v.x * wi;
            bacc[s].y += v.y * wi;
            bacc[s].z += v.z * wi;
            bacc[s].w += v.w * wi;
        }
        // wave-reduce the row dot-product -> f[b][i]
#pragma unroll
        for (int off = 32; off; off >>= 1) p += __shfl_down(p, off, 64);
        if (lane == 0) f[(size_t)b * N + i] = p;
    }

    // combine the 4 waves' column partials via LDS
#pragma unroll
    for (int s = 0; s < 4; ++s)
        reinterpret_cast<float4*>(lds_b[wave])[lane + 64 * s] = bacc[s];
    __syncthreads();

    float4 s0 = reinterpret_cast<float4*>(lds_b[0])[t];
    float4 s1 = reinterpret_cast<float4*>(lds_b[1])[t];
    float4 s2 = reinterpret_cast<float4*>(lds_b[2])[t];
    float4 s3 = reinterpret_cast<float4*>(lds_b[3])[t];
    float4 o;
    o.x = s0.x + s1.x + s2.x + s3.x;
    o.y = s0.y + s1.y + s2.y + s3.y;
    o.z = s0.z + s1.z + s2.z + s3.z;
    o.w = s0.w + s1.w + s2.w + s3.w;
    reinterpret_cast<float4*>(bpart + ((size_t)b * CHUNKS_A + chunk) * N)[t] = o;
}

// -------- Kernel B: logits[b][n] = beta * sim / (||mem_row||*||k|| + EPS) --------
__global__ __launch_bounds__(256) void kB(const float* __restrict__ mem,
                                          const float* __restrict__ keys,
                                          const float* __restrict__ strengths,
                                          const int* __restrict__ head,
                                          float* __restrict__ logits) {
    int h    = head[0];
    int bid  = blockIdx.x;
    int b    = bid / (N / 4);
    int c    = bid % (N / 4);
    int lane = threadIdx.x & 63, wave = threadIdx.x >> 6;
    int n    = c * 4 + wave;

    float2 kv = reinterpret_cast<const float2*>(keys + ((size_t)b * H + h) * M)[lane];
    float2 mv = reinterpret_cast<const float2*>(mem + ((size_t)b * N + n) * M)[lane];

    float dot = mv.x * kv.x + mv.y * kv.y;
    float sm  = mv.x * mv.x + mv.y * mv.y;
    float sk  = kv.x * kv.x + kv.y * kv.y;
#pragma unroll
    for (int off = 32; off; off >>= 1) {
        dot += __shfl_down(dot, off, 64);
        sm  += __shfl_down(sm, off, 64);
        sk  += __shfl_down(sk, off, 64);
    }
    if (lane == 0) {
        float beta  = strengths[(size_t)b * H + h];
        float denom = sqrtf(sm) * sqrtf(sk) + EPS;
        logits[(size_t)b * N + n] = beta * dot / denom;
    }
}

// -------- Kernel C1: per-batch softmax + mode combine -> W --------
__global__ __launch_bounds__(256) void kC1(const float* __restrict__ f,
                                           const float* __restrict__ bpart,
                                           const float* __restrict__ logits,
                                           const float* __restrict__ mode,
                                           const int* __restrict__ head,
                                           float* __restrict__ Wout) {
    int b = blockIdx.x;
    int t = threadIdx.x;
    int h = head[0];
    int lane = t & 63, wave = t >> 6;
    __shared__ float redmax[4];
    __shared__ float redsum[4];

    float lg[4], bs[4], fv[4];
    float mx = -1e30f;
#pragma unroll
    for (int q = 0; q < 4; ++q) {
        int n = t + 256 * q;
        lg[q] = logits[(size_t)b * N + n];
        fv[q] = f[(size_t)b * N + n];
        float s = 0.f;
        for (int c = 0; c < CHUNKS_A; ++c)
            s += bpart[((size_t)b * CHUNKS_A + c) * N + n];
        bs[q] = s;
        mx = fmaxf(mx, lg[q]);
    }
#pragma unroll
    for (int off = 32; off; off >>= 1) mx = fmaxf(mx, __shfl_down(mx, off, 64));
    if (lane == 0) redmax[wave] = mx;
    __syncthreads();
    mx = fmaxf(fmaxf(redmax[0], redmax[1]), fmaxf(redmax[2], redmax[3]));

    float ex[4];
    float se = 0.f;
#pragma unroll
    for (int q = 0; q < 4; ++q) { ex[q] = expf(lg[q] - mx); se += ex[q]; }
#pragma unroll
    for (int off = 32; off; off >>= 1) se += __shfl_down(se, off, 64);
    if (lane == 0) redsum[wave] = se;
    __syncthreads();
    se = redsum[0] + redsum[1] + redsum[2] + redsum[3];
    float inv = 1.f / se;

    const float* rm = mode + ((size_t)b * H + h) * 3;
    float rm0 = rm[0], rm1 = rm[1], rm2 = rm[2];
#pragma unroll
    for (int q = 0; q < 4; ++q) {
        int n = t + 256 * q;
        Wout[(size_t)b * N + n] = rm0 * bs[q] + rm1 * ex[q] * inv + rm2 * fv[q];
    }
}

// -------- Kernel C2: partial mem_content over row chunks --------
__global__ __launch_bounds__(256) void kC2(const float* __restrict__ mem,
                                           const float* __restrict__ Wout,
                                           float* __restrict__ mcpart) {
    int bid   = blockIdx.x;
    int b     = bid / CHUNKS_C2;
    int chunk = bid % CHUNKS_C2;
    int t     = threadIdx.x;
    int cg    = t & 31;   // column group -> cols 4cg..4cg+3
    int rg    = t >> 5;   // row subgroup 0..7
    __shared__ float4 lds[8][32];

    float4 acc = make_float4(0.f, 0.f, 0.f, 0.f);
    int r0 = chunk * ROWS_C2;
#pragma unroll
    for (int rr = 0; rr < ROWS_C2 / 8; ++rr) {
        int n   = r0 + rg + rr * 8;
        float w = Wout[(size_t)b * N + n];
        float4 v = reinterpret_cast<const float4*>(mem + ((size_t)b * N + n) * M)[cg];
        acc.x += w * v.x; acc.y += w * v.y; acc.z += w * v.z; acc.w += w * v.w;
    }
    lds[rg][cg] = acc;
    __syncthreads();
    if (t < 32) {
        float4 o = make_float4(0.f, 0.f, 0.f, 0.f);
#pragma unroll
        for (int g = 0; g < 8; ++g) {
            float4 v = lds[g][t];
            o.x += v.x; o.y += v.y; o.z += v.z; o.w += v.w;
        }
        reinterpret_cast<float4*>(mcpart + ((size_t)b * CHUNKS_C2 + chunk) * M)[t] = o;
    }
}

// -------- Kernel C3: reduce mem_content partials --------
__global__ __launch_bounds__(256) void kC3(const float* __restrict__ mcpart,
                                           float* __restrict__ mc) {
    int idx = blockIdx.x * 256 + threadIdx.x;   // B*M = 4096
    if (idx >= B * M) return;
    int b = idx / M, m = idx % M;
    float s = 0.f;
    for (int c = 0; c < CHUNKS_C2; ++c)
        s += mcpart[((size_t)b * CHUNKS_C2 + c) * M + m];
    mc[idx] = s;
}

extern "C" void kernel_launch(void* const* d_in, const int* in_sizes, int n_in,
                              void* d_out, int out_size, void* d_ws, size_t ws_size,
                              hipStream_t stream) {
    const float* read_keys      = (const float*)d_in[0];
    const float* read_strengths = (const float*)d_in[1];
    const float* read_mode      = (const float*)d_in[2];
    const float* W_old          = (const float*)d_in[3];
    const float* L              = (const float*)d_in[4];
    const float* memory         = (const float*)d_in[5];
    const int*   head_no        = (const int*)d_in[6];

    float* out_W  = (float*)d_out;             // B*N
    float* out_mc = out_W + (size_t)B * N;     // B*M

    float* ws     = (float*)d_ws;
    float* f      = ws;                                   // B*N
    float* bpart  = f + (size_t)B * N;                    // B*CHUNKS_A*N
    float* logits = bpart + (size_t)B * CHUNKS_A * N;     // B*N
    float* mcpart = logits + (size_t)B * N;               // B*CHUNKS_C2*M

    kA<<<B * CHUNKS_A, 256, 0, stream>>>(L, W_old, f, bpart);
    kB<<<B * (N / 4), 256, 0, stream>>>(memory, read_keys, read_strengths, head_no, logits);
    kC1<<<B, 256, 0, stream>>>(f, bpart, logits, read_mode, head_no, out_W);
    kC2<<<B * CHUNKS_C2, 256, 0, stream>>>(memory, out_W, mcpart);
    kC3<<<(B * M + 255) / 256, 256, 0, stream>>>(mcpart, out_mc);
}

// Round 2
// 41.266 us; speedup vs baseline: 1.0681x; 1.0681x over previous
//
#include <hip/hip_runtime.h>
#include <math.h>

#define EPS 1e-8f

constexpr int B = 32, N = 1024, M = 128, H = 2;

constexpr int ROWS_A   = 16;            // rows of L per A-block
constexpr int CHUNKS_A = N / ROWS_A;    // 64
constexpr int NBLK_A   = B * CHUNKS_A;  // 2048
constexpr int ROWS_B   = 64;            // memory rows per B-block
constexpr int NBLK_B   = B * (N / ROWS_B); // 512
constexpr int ROWS_C   = 64;            // memory rows per K2 block
constexpr int CHUNKS_C = N / ROWS_C;    // 16

// ---- K1: fused. A-blocks: f = L w and bpart (column partials of L^T w).
// ----           B-blocks: e[b][n] = exp(beta * cos_sim(mem[n], k)).
__global__ __launch_bounds__(256) void k1(const float* __restrict__ L,
                                          const float* __restrict__ Wold,
                                          const float* __restrict__ mem,
                                          const float* __restrict__ keys,
                                          const float* __restrict__ strengths,
                                          const int* __restrict__ head,
                                          float* __restrict__ f,
                                          float* __restrict__ bpart,
                                          float* __restrict__ e) {
    int bid  = blockIdx.x;
    int t    = threadIdx.x;
    int lane = t & 63, wave = t >> 6;

    if (bid < NBLK_A) {
        __shared__ float sw[N];
        __shared__ float lds_b[4][N];

        int b     = bid / CHUNKS_A;
        int chunk = bid % CHUNKS_A;

        reinterpret_cast<float4*>(sw)[t] =
            reinterpret_cast<const float4*>(Wold + (size_t)b * N)[t];
        __syncthreads();

        float4 wreg[4];
        float4 bacc[4];
#pragma unroll
        for (int s = 0; s < 4; ++s) {
            wreg[s] = reinterpret_cast<float4*>(sw)[lane + 64 * s];
            bacc[s] = make_float4(0.f, 0.f, 0.f, 0.f);
        }

        const float* Lb = L + (size_t)b * N * N;
        int r0 = chunk * ROWS_A;
        for (int r = wave; r < ROWS_A; r += 4) {      // 4 rows per wave
            int i = r0 + r;
            const float4* row = reinterpret_cast<const float4*>(Lb + (size_t)i * N);
            float wi = sw[i];
            float p  = 0.f;
#pragma unroll
            for (int s = 0; s < 4; ++s) {
                float4 v = row[lane + 64 * s];
                p += v.x * wreg[s].x + v.y * wreg[s].y + v.z * wreg[s].z + v.w * wreg[s].w;
                bacc[s].x += v.x * wi;
                bacc[s].y += v.y * wi;
                bacc[s].z += v.z * wi;
                bacc[s].w += v.w * wi;
            }
#pragma unroll
            for (int off = 32; off; off >>= 1) p += __shfl_down(p, off, 64);
            if (lane == 0) f[(size_t)b * N + i] = p;
        }

#pragma unroll
        for (int s = 0; s < 4; ++s)
            reinterpret_cast<float4*>(lds_b[wave])[lane + 64 * s] = bacc[s];
        __syncthreads();

        float4 s0 = reinterpret_cast<float4*>(lds_b[0])[t];
        float4 s1 = reinterpret_cast<float4*>(lds_b[1])[t];
        float4 s2 = reinterpret_cast<float4*>(lds_b[2])[t];
        float4 s3 = reinterpret_cast<float4*>(lds_b[3])[t];
        float4 o;
        o.x = s0.x + s1.x + s2.x + s3.x;
        o.y = s0.y + s1.y + s2.y + s3.y;
        o.z = s0.z + s1.z + s2.z + s3.z;
        o.w = s0.w + s1.w + s2.w + s3.w;
        reinterpret_cast<float4*>(bpart + ((size_t)b * CHUNKS_A + chunk) * N)[t] = o;
    } else {
        int id    = bid - NBLK_A;
        int b     = id / (N / ROWS_B);
        int chunk = id % (N / ROWS_B);
        int half  = lane >> 5;
        int l32   = lane & 31;
        int h     = head[0];

        float4 kv = reinterpret_cast<const float4*>(keys + ((size_t)b * H + h) * M)[l32];
        float  sk = kv.x * kv.x + kv.y * kv.y + kv.z * kv.z + kv.w * kv.w;
#pragma unroll
        for (int off = 16; off; off >>= 1) sk += __shfl_xor(sk, off, 64);
        float norm_k = sqrtf(sk);
        float beta   = strengths[(size_t)b * H + h];

        int r0 = chunk * ROWS_B;
#pragma unroll
        for (int rr = 0; rr < ROWS_B / 8; ++rr) {     // wave handles 2 rows/iter
            int n = r0 + rr * 8 + wave * 2 + half;
            float4 mv = reinterpret_cast<const float4*>(mem + ((size_t)b * N + n) * M)[l32];
            float dot = mv.x * kv.x + mv.y * kv.y + mv.z * kv.z + mv.w * kv.w;
            float sm  = mv.x * mv.x + mv.y * mv.y + mv.z * mv.z + mv.w * mv.w;
#pragma unroll
            for (int off = 16; off; off >>= 1) {
                dot += __shfl_xor(dot, off, 64);
                sm  += __shfl_xor(sm, off, 64);
            }
            if (l32 == 0) {
                float denom = sqrtf(sm) * norm_k + EPS;
                e[(size_t)b * N + n] = expf(beta * dot / denom);
            }
        }
    }
}

// ---- K2: per 64-row chunk: bsum from bpart, U = rm0*bsum + rm2*f (stored),
// ----     partial mcU += U*mem, mcE += e*mem, epart = chunk-sum of e.
__global__ __launch_bounds__(256) void k2(const float* __restrict__ mem,
                                          const float* __restrict__ bpart,
                                          const float* __restrict__ f,
                                          const float* __restrict__ e,
                                          const float* __restrict__ mode,
                                          const int* __restrict__ head,
                                          float* __restrict__ U,
                                          float* __restrict__ mcU,
                                          float* __restrict__ mcE,
                                          float* __restrict__ epart) {
    int bid   = blockIdx.x;
    int b     = bid / CHUNKS_C;
    int chunk = bid % CHUNKS_C;
    int t     = threadIdx.x;
    int r0    = chunk * ROWS_C;

    __shared__ float bp[4][ROWS_C];
    __shared__ float su[ROWS_C], se[ROWS_C];
    __shared__ float4 lU[8][32];
    __shared__ float4 lE[8][32];

    // phase 1: bsum partials over CHUNKS_A, split across 4 c-groups
    int n_ = t & 63, cg_ = t >> 6;
    float s = 0.f;
    for (int c = cg_; c < CHUNKS_A; c += 4)
        s += bpart[((size_t)b * CHUNKS_A + c) * N + r0 + n_];
    bp[cg_][n_] = s;
    __syncthreads();

    int h = head[0];
    const float* rm = mode + ((size_t)b * H + h) * 3;
    if (t < ROWS_C) {
        float bsum = bp[0][t] + bp[1][t] + bp[2][t] + bp[3][t];
        float u = rm[0] * bsum + rm[2] * f[(size_t)b * N + r0 + t];
        su[t] = u;
        U[(size_t)b * N + r0 + t] = u;
        se[t] = e[(size_t)b * N + r0 + t];
    }
    __syncthreads();

    // phase 2: mc partials
    int cg = t & 31, rg = t >> 5;
    float4 aU = make_float4(0.f, 0.f, 0.f, 0.f);
    float4 aE = make_float4(0.f, 0.f, 0.f, 0.f);
#pragma unroll
    for (int rr = 0; rr < ROWS_C / 8; ++rr) {
        int r = rg + rr * 8;
        float4 v = reinterpret_cast<const float4*>(mem + ((size_t)b * N + r0 + r) * M)[cg];
        float uu = su[r], ee = se[r];
        aU.x += uu * v.x; aU.y += uu * v.y; aU.z += uu * v.z; aU.w += uu * v.w;
        aE.x += ee * v.x; aE.y += ee * v.y; aE.z += ee * v.z; aE.w += ee * v.w;
    }
    lU[rg][cg] = aU;
    lE[rg][cg] = aE;
    __syncthreads();

    if (t < 32) {
        float4 oU = make_float4(0.f, 0.f, 0.f, 0.f);
        float4 oE = make_float4(0.f, 0.f, 0.f, 0.f);
#pragma unroll
        for (int g = 0; g < 8; ++g) {
            float4 vU = lU[g][t], vE = lE[g][t];
            oU.x += vU.x; oU.y += vU.y; oU.z += vU.z; oU.w += vU.w;
            oE.x += vE.x; oE.y += vE.y; oE.z += vE.z; oE.w += vE.w;
        }
        reinterpret_cast<float4*>(mcU + ((size_t)b * CHUNKS_C + chunk) * M)[t] = oU;
        reinterpret_cast<float4*>(mcE + ((size_t)b * CHUNKS_C + chunk) * M)[t] = oE;
    } else if (t >= 64 && t < 128) {
        float val = se[t - 64];
#pragma unroll
        for (int off = 32; off; off >>= 1) val += __shfl_down(val, off, 64);
        if (t == 64) epart[(size_t)b * CHUNKS_C + chunk] = val;
    }
}

// ---- K3: finalize. S = sum(epart); W = U + (rm1/S)*e; mc = sum(mcU) + (rm1/S)*sum(mcE).
__global__ __launch_bounds__(256) void k3(const float* __restrict__ U,
                                          const float* __restrict__ e,
                                          const float* __restrict__ mcU,
                                          const float* __restrict__ mcE,
                                          const float* __restrict__ epart,
                                          const float* __restrict__ mode,
                                          const int* __restrict__ head,
                                          float* __restrict__ outW,
                                          float* __restrict__ outMC) {
    int b = blockIdx.x;
    int t = threadIdx.x;
    int h = head[0];
    float rm1 = mode[((size_t)b * H + h) * 3 + 1];

    float S = 0.f;
#pragma unroll
    for (int c = 0; c < CHUNKS_C; ++c) S += epart[(size_t)b * CHUNKS_C + c];
    float coef = rm1 / S;

#pragma unroll
    for (int q = 0; q < 4; ++q) {
        int n = t + 256 * q;
        outW[(size_t)b * N + n] = U[(size_t)b * N + n] + coef * e[(size_t)b * N + n];
    }
    if (t < M) {
        float sU = 0.f, sE = 0.f;
#pragma unroll
        for (int c = 0; c < CHUNKS_C; ++c) {
            sU += mcU[((size_t)b * CHUNKS_C + c) * M + t];
            sE += mcE[((size_t)b * CHUNKS_C + c) * M + t];
        }
        outMC[(size_t)b * M + t] = sU + coef * sE;
    }
}

extern "C" void kernel_launch(void* const* d_in, const int* in_sizes, int n_in,
                              void* d_out, int out_size, void* d_ws, size_t ws_size,
                              hipStream_t stream) {
    const float* read_keys      = (const float*)d_in[0];
    const float* read_strengths = (const float*)d_in[1];
    const float* read_mode      = (const float*)d_in[2];
    const float* W_old          = (const float*)d_in[3];
    const float* L              = (const float*)d_in[4];
    const float* memory         = (const float*)d_in[5];
    const int*   head_no        = (const int*)d_in[6];

    float* out_W  = (float*)d_out;             // B*N
    float* out_mc = out_W + (size_t)B * N;     // B*M

    float* ws    = (float*)d_ws;
    float* f     = ws;                                    // B*N
    float* bpart = f + (size_t)B * N;                     // B*CHUNKS_A*N (8 MB)
    float* e     = bpart + (size_t)B * CHUNKS_A * N;      // B*N
    float* Ubuf  = e + (size_t)B * N;                     // B*N
    float* mcU   = Ubuf + (size_t)B * N;                  // B*CHUNKS_C*M
    float* mcE   = mcU + (size_t)B * CHUNKS_C * M;        // B*CHUNKS_C*M
    float* epart = mcE + (size_t)B * CHUNKS_C * M;        // B*CHUNKS_C

    k1<<<NBLK_A + NBLK_B, 256, 0, stream>>>(L, W_old, memory, read_keys,
                                            read_strengths, head_no, f, bpart, e);
    k2<<<B * CHUNKS_C, 256, 0, stream>>>(memory, bpart, f, e, read_mode, head_no,
                                         Ubuf, mcU, mcE, epart);
    k3<<<B, 256, 0, stream>>>(Ubuf, e, mcU, mcE, epart, read_mode, head_no,
                              out_W, out_mc);
}